// Round 8
// baseline (589.939 us; speedup 1.0000x reference)
//
#include <hip/hip_runtime.h>

// 2-branch PolyConv GNN + MLP head. float32, int32 indices.
// f_k = L^k h, L(f) = f - dinv*S(f*dinv). Filters = linear combos of f_0,f_1,f_2:
//   ortho: o0 = 3f0-3f1+0.75f2, o1 = 3f1-1.5f2, o2 = 0.75f2
//   sim:   all three = 4(f0+f1+f2)
// R8: (1) dense f-buffers in d_ws (gather working set 12.8 MB contiguous vs
// 256B slots spread over 77 MB -> better L2 hit rate); runtime fallback to the
// R7 hall-slot flow if ws_size is too small. (2) theta combines fused into
// hop2 epilogue (race-free: hop2 sources live in ws, hall written own-node
// only). (3) merged count/fill/gemm launches; fill cursor = d2d copy of row
// (drops the random row[d] read); gather unrolled 8-deep.

__global__ __launch_bounds__(256) void count2_kernel(
    const int* __restrict__ dst_o, const int* __restrict__ dst_s,
    int* __restrict__ cnt, int E, int Es, int eb, int N) {
    int b = blockIdx.x;
    if (b < eb) {
        int e = b * 256 + threadIdx.x;
        if (e < E) atomicAdd(&cnt[dst_o[e]], 1);
    } else {
        int e = (b - eb) * 256 + threadIdx.x;
        if (e < Es) atomicAdd(&cnt[N + dst_s[e]], 1);
    }
}

// Phase 1: per-1024-chunk sums. grid = 2*B, cnt = [graph0 N | graph1 N].
__global__ __launch_bounds__(256) void scan_p1(const int* __restrict__ cnt,
                                               int* __restrict__ part, int N, int B) {
    int g = blockIdx.x / B, c = blockIdx.x - g * B;
    const int* p = cnt + (long)g * N;
    int tid = threadIdx.x, base = c << 10;
    int s = 0;
    #pragma unroll
    for (int q = 0; q < 4; ++q) {
        int i = base + q * 256 + tid;
        if (i < N) s += p[i];
    }
    #pragma unroll
    for (int off = 32; off > 0; off >>= 1) s += __shfl_down(s, off);
    __shared__ int ws[4];
    if ((tid & 63) == 0) ws[tid >> 6] = s;
    __syncthreads();
    if (tid == 0) part[blockIdx.x] = ws[0] + ws[1] + ws[2] + ws[3];
}

// Phase 2: exclusive scan of B partials per graph (B <= 64). grid = 2 x 64.
__global__ __launch_bounds__(64) void scan_p2(int* __restrict__ part,
                                              int* __restrict__ row_o,
                                              int* __restrict__ row_s, int N, int B) {
    int g = blockIdx.x, t = threadIdx.x;
    int v = (t < B) ? part[g * B + t] : 0;
    int inc = v;
    #pragma unroll
    for (int off = 1; off < 64; off <<= 1) {
        int u = __shfl_up(inc, off);
        if (t >= off) inc += u;
    }
    if (t < B) part[g * B + t] = inc - v;
    int total = __shfl(inc, 63);
    if (t == 0) (g == 0 ? row_o : row_s)[N] = total;
}

// Phase 3: block-local exclusive scan + chunk offset -> row; dinv fused.
__global__ __launch_bounds__(256) void scan_p3(const int* __restrict__ cnt,
                                               const int* __restrict__ part,
                                               int* __restrict__ row_o, int* __restrict__ row_s,
                                               float* __restrict__ dinv, int N, int B) {
    int g = blockIdx.x / B, c = blockIdx.x - g * B;
    int tid = threadIdx.x;
    int base = (c << 10) + tid * 4;
    const int* p = cnt + (long)g * N;
    int* row = (g == 0) ? row_o : row_s;
    float* dv = dinv + (long)g * N;
    int v[4];
    #pragma unroll
    for (int q = 0; q < 4; ++q) { int i = base + q; v[q] = (i < N) ? p[i] : 0; }
    int s = v[0] + v[1] + v[2] + v[3];
    int inc = s;
    #pragma unroll
    for (int off = 1; off < 64; off <<= 1) {
        int u = __shfl_up(inc, off);
        if ((tid & 63) >= off) inc += u;
    }
    __shared__ int wt[4];
    if ((tid & 63) == 63) wt[tid >> 6] = inc;
    __syncthreads();
    int wo = 0;
    for (int w = 0; w < (tid >> 6); ++w) wo += wt[w];
    int ex = part[blockIdx.x] + wo + inc - s;
    #pragma unroll
    for (int q = 0; q < 4; ++q) {
        int i = base + q;
        if (i < N) {
            row[i] = ex;
            dv[i] = rsqrtf((float)(v[q] > 1 ? v[q] : 1));
            ex += v[q];
        }
    }
}

// cur preloaded with row values (d2d copy); pos = atomicAdd(cur) directly.
__global__ __launch_bounds__(256) void fill2_kernel(
    const int* __restrict__ src_o, const int* __restrict__ dst_o,
    const int* __restrict__ src_s, const int* __restrict__ dst_s,
    int* __restrict__ cur, int* __restrict__ esrc_o, int* __restrict__ esrc_s,
    int E, int Es, int eb, int N) {
    int b = blockIdx.x;
    if (b < eb) {
        int e = b * 256 + threadIdx.x;
        if (e < E) {
            int d = dst_o[e];
            esrc_o[atomicAdd(&cur[d], 1)] = src_o[e];
        }
    } else {
        int e = (b - eb) * 256 + threadIdx.x;
        if (e < Es) {
            int d = dst_s[e];
            esrc_s[atomicAdd(&cur[N + d], 1)] = src_s[e];
        }
    }
}

// Both input GEMMs in one launch. out[node*ld + tx*4..] = relu(x@W + b); K=128.
__global__ __launch_bounds__(256) void in_gemm2_kernel(
    const float* __restrict__ x_o, const float* __restrict__ W_o, const float* __restrict__ b_o,
    float* __restrict__ out_o, int ld_o,
    const float* __restrict__ x_s, const float* __restrict__ W_s, const float* __restrict__ b_s,
    float* __restrict__ out_s, int ld_s, int n, int nb) {
    __shared__ float xs[64][132];
    __shared__ float Wf[128][68];
    int blk = blockIdx.x;
    const float* x; const float* W; const float* b; float* out; int ld;
    if (blk < nb) { x = x_o; W = W_o; b = b_o; out = out_o; ld = ld_o; }
    else { blk -= nb; x = x_s; W = W_s; b = b_s; out = out_s; ld = ld_s; }
    int tid = threadIdx.x;
    int node0 = blk * 64;
    const float4* wsrc = (const float4*)W;
    for (int i = tid; i < 2048; i += 256)
        *(float4*)&Wf[i >> 4][(i & 15) * 4] = wsrc[i];
    const float4* xsrc = (const float4*)x;
    for (int i = tid; i < 2048; i += 256) {
        int nl = i >> 5, c = i & 31;
        int node = node0 + nl;
        float4 v = make_float4(0.f, 0.f, 0.f, 0.f);
        if (node < n) v = xsrc[(long)node * 32 + c];
        *(float4*)&xs[nl][c * 4] = v;
    }
    __syncthreads();
    int tx = tid & 15, ty = tid >> 4;
    float acc[4][4] = {};
    #pragma unroll 2
    for (int k = 0; k < 128; k += 4) {
        float4 a[4], bb[4];
        #pragma unroll
        for (int i = 0; i < 4; ++i) a[i] = *(const float4*)&xs[ty * 4 + i][k];
        #pragma unroll
        for (int j = 0; j < 4; ++j) bb[j] = *(const float4*)&Wf[k + j][tx * 4];
        #pragma unroll
        for (int i = 0; i < 4; ++i) {
            acc[i][0] = fmaf(a[i].x, bb[0].x, acc[i][0]);
            acc[i][1] = fmaf(a[i].x, bb[0].y, acc[i][1]);
            acc[i][2] = fmaf(a[i].x, bb[0].z, acc[i][2]);
            acc[i][3] = fmaf(a[i].x, bb[0].w, acc[i][3]);
            acc[i][0] = fmaf(a[i].y, bb[1].x, acc[i][0]);
            acc[i][1] = fmaf(a[i].y, bb[1].y, acc[i][1]);
            acc[i][2] = fmaf(a[i].y, bb[1].z, acc[i][2]);
            acc[i][3] = fmaf(a[i].y, bb[1].w, acc[i][3]);
            acc[i][0] = fmaf(a[i].z, bb[2].x, acc[i][0]);
            acc[i][1] = fmaf(a[i].z, bb[2].y, acc[i][1]);
            acc[i][2] = fmaf(a[i].z, bb[2].z, acc[i][2]);
            acc[i][3] = fmaf(a[i].z, bb[2].w, acc[i][3]);
            acc[i][0] = fmaf(a[i].w, bb[3].x, acc[i][0]);
            acc[i][1] = fmaf(a[i].w, bb[3].y, acc[i][1]);
            acc[i][2] = fmaf(a[i].w, bb[3].z, acc[i][2]);
            acc[i][3] = fmaf(a[i].w, bb[3].w, acc[i][3]);
        }
    }
    float4 bias = *(const float4*)&b[tx * 4];
    #pragma unroll
    for (int i = 0; i < 4; ++i) {
        int node = node0 + ty * 4 + i;
        if (node >= n) break;
        float4 r;
        r.x = fmaxf(acc[i][0] + bias.x, 0.0f);
        r.y = fmaxf(acc[i][1] + bias.y, 0.0f);
        r.z = fmaxf(acc[i][2] + bias.z, 0.0f);
        r.w = fmaxf(acc[i][3] + bias.w, 0.0f);
        *(float4*)&out[(long)node * ld + tx * 4] = r;
    }
}

// Merged CSR gather SpMV for BOTH graphs; generic in/out strides.
// mode 0: plain hop -> fout[d*sout + lane] = f_in[d] - acc*dinv[d]
// mode 1: final hop + fused theta combine -> hall (own-node slots only).
//   Race-free in mode 1 iff fin/f0 buffers are not written by this kernel.
__global__ __launch_bounds__(256) void gather2x_kernel(
    const int* __restrict__ row_o, const int* __restrict__ esrc_o, const float* __restrict__ dinv_o,
    const int* __restrict__ row_s, const int* __restrict__ esrc_s, const float* __restrict__ dinv_s,
    const float* __restrict__ fin_o, int sin_o, const float* __restrict__ fin_s, int sin_s,
    float* __restrict__ fout_o, int sout_o, float* __restrict__ fout_s, int sout_s,
    const float* __restrict__ f0_o, int s0_o, const float* __restrict__ f0_s, int s0_s,
    float* __restrict__ hall, int mode, int n, int nb) {
    int b = blockIdx.x, g;
    const int* row; const int* esrc; const float* dinv; const float* fin; int sin;
    if (b < nb) { g = 0; row = row_o; esrc = esrc_o; dinv = dinv_o; fin = fin_o; sin = sin_o; }
    else { g = 1; b -= nb; row = row_s; esrc = esrc_s; dinv = dinv_s; fin = fin_s; sin = sin_s; }
    int d = b * 4 + (threadIdx.x >> 6);
    if (d >= n) return;
    int lane = threadIdx.x & 63;
    int p = row[d], end = row[d + 1];
    float a0 = 0.f, a1 = 0.f, a2 = 0.f, a3 = 0.f, a4 = 0.f, a5 = 0.f, a6 = 0.f, a7 = 0.f;
    for (; p + 8 <= end; p += 8) {
        int s0 = esrc[p],     s1 = esrc[p + 1], s2 = esrc[p + 2], s3 = esrc[p + 3];
        int s4 = esrc[p + 4], s5 = esrc[p + 5], s6 = esrc[p + 6], s7 = esrc[p + 7];
        a0 = fmaf(fin[(long)s0 * sin + lane], dinv[s0], a0);
        a1 = fmaf(fin[(long)s1 * sin + lane], dinv[s1], a1);
        a2 = fmaf(fin[(long)s2 * sin + lane], dinv[s2], a2);
        a3 = fmaf(fin[(long)s3 * sin + lane], dinv[s3], a3);
        a4 = fmaf(fin[(long)s4 * sin + lane], dinv[s4], a4);
        a5 = fmaf(fin[(long)s5 * sin + lane], dinv[s5], a5);
        a6 = fmaf(fin[(long)s6 * sin + lane], dinv[s6], a6);
        a7 = fmaf(fin[(long)s7 * sin + lane], dinv[s7], a7);
    }
    for (; p < end; ++p) {
        int s = esrc[p];
        a0 = fmaf(fin[(long)s * sin + lane], dinv[s], a0);
    }
    float acc = ((a0 + a1) + (a2 + a3)) + ((a4 + a5) + (a6 + a7));
    float f1v = fin[(long)d * sin + lane];
    float f2v = f1v - acc * dinv[d];
    if (mode == 0) {
        if (g == 0) fout_o[(long)d * sout_o + lane] = f2v;
        else        fout_s[(long)d * sout_s + lane] = f2v;
    } else {
        long ob = (long)d * 384 + lane;
        if (g == 0) {
            float f0v = f0_o[(long)d * s0_o + lane];
            hall[ob]       = 3.0f * f0v - 3.0f * f1v + 0.75f * f2v;
            hall[ob + 64]  = 3.0f * f1v - 1.5f * f2v;
            hall[ob + 128] = 0.75f * f2v;
        } else {
            float f0v = f0_s[(long)d * s0_s + lane];
            float ss = 4.0f * (f0v + f1v + f2v);
            hall[ob + 192] = ss; hall[ob + 256] = ss; hall[ob + 320] = ss;
        }
    }
}

// Fallback-path combine (both branches, node-local).
__global__ __launch_bounds__(256) void combine_kernel(float* __restrict__ h, int nf) {
    int i = blockIdx.x * 256 + threadIdx.x;
    if (i >= nf) return;
    long ob = (long)(i >> 6) * 384 + (i & 63);
    float f0v = h[ob], f1v = h[ob + 64], f2v = h[ob + 128];
    h[ob]       = 3.0f * f0v - 3.0f * f1v + 0.75f * f2v;
    h[ob + 64]  = 3.0f * f1v - 1.5f * f2v;
    h[ob + 128] = 0.75f * f2v;
    float ss = 4.0f * (h[ob + 192] + h[ob + 256] + h[ob + 320]);
    h[ob + 192] = ss; h[ob + 256] = ss; h[ob + 320] = ss;
}

// logits = relu(h_all @ Wm1 + bm1) @ Wm2 + bm2. Tiled, K=384 in 3 chunks.
__global__ __launch_bounds__(256) void mlp_kernel(
    const float* __restrict__ hall, const float* __restrict__ Wm1,
    const float* __restrict__ bm1, const float* __restrict__ Wm2,
    const float* __restrict__ bm2, float* __restrict__ logits, int n) {
    __shared__ float xs[64][132];
    __shared__ float Wf[128][68];
    int tid = threadIdx.x;
    int node0 = blockIdx.x * 64;
    int tx = tid & 15, ty = tid >> 4;
    float acc[4][4] = {};
    const float4* wsrc = (const float4*)Wm1;
    const float4* hsrc = (const float4*)hall;
    for (int c = 0; c < 3; ++c) {
        __syncthreads();
        for (int i = tid; i < 2048; i += 256)
            *(float4*)&Wf[i >> 4][(i & 15) * 4] = wsrc[c * 2048 + i];
        for (int i = tid; i < 2048; i += 256) {
            int nl = i >> 5, cc = i & 31;
            int node = node0 + nl;
            float4 v = make_float4(0.f, 0.f, 0.f, 0.f);
            if (node < n) v = hsrc[(long)node * 96 + c * 32 + cc];
            *(float4*)&xs[nl][cc * 4] = v;
        }
        __syncthreads();
        #pragma unroll 2
        for (int k = 0; k < 128; k += 4) {
            float4 a[4], bb[4];
            #pragma unroll
            for (int i = 0; i < 4; ++i) a[i] = *(const float4*)&xs[ty * 4 + i][k];
            #pragma unroll
            for (int j = 0; j < 4; ++j) bb[j] = *(const float4*)&Wf[k + j][tx * 4];
            #pragma unroll
            for (int i = 0; i < 4; ++i) {
                acc[i][0] = fmaf(a[i].x, bb[0].x, acc[i][0]);
                acc[i][1] = fmaf(a[i].x, bb[0].y, acc[i][1]);
                acc[i][2] = fmaf(a[i].x, bb[0].z, acc[i][2]);
                acc[i][3] = fmaf(a[i].x, bb[0].w, acc[i][3]);
                acc[i][0] = fmaf(a[i].y, bb[1].x, acc[i][0]);
                acc[i][1] = fmaf(a[i].y, bb[1].y, acc[i][1]);
                acc[i][2] = fmaf(a[i].y, bb[1].z, acc[i][2]);
                acc[i][3] = fmaf(a[i].y, bb[1].w, acc[i][3]);
                acc[i][0] = fmaf(a[i].z, bb[2].x, acc[i][0]);
                acc[i][1] = fmaf(a[i].z, bb[2].y, acc[i][1]);
                acc[i][2] = fmaf(a[i].z, bb[2].z, acc[i][2]);
                acc[i][3] = fmaf(a[i].z, bb[2].w, acc[i][3]);
                acc[i][0] = fmaf(a[i].w, bb[3].x, acc[i][0]);
                acc[i][1] = fmaf(a[i].w, bb[3].y, acc[i][1]);
                acc[i][2] = fmaf(a[i].w, bb[3].z, acc[i][2]);
                acc[i][3] = fmaf(a[i].w, bb[3].w, acc[i][3]);
            }
        }
    }
    __syncthreads();
    float4 bias = *(const float4*)&bm1[tx * 4];
    #pragma unroll
    for (int i = 0; i < 4; ++i) {
        xs[ty * 4 + i][tx * 4 + 0] = fmaxf(acc[i][0] + bias.x, 0.0f);
        xs[ty * 4 + i][tx * 4 + 1] = fmaxf(acc[i][1] + bias.y, 0.0f);
        xs[ty * 4 + i][tx * 4 + 2] = fmaxf(acc[i][2] + bias.z, 0.0f);
        xs[ty * 4 + i][tx * 4 + 3] = fmaxf(acc[i][3] + bias.w, 0.0f);
    }
    __syncthreads();
    if (tid < 128) {
        int nl = tid >> 1, o = tid & 1;
        int node = node0 + nl;
        if (node < n) {
            float p = bm2[o];
            #pragma unroll 8
            for (int k = 0; k < 64; ++k) p = fmaf(xs[nl][k], Wm2[k * 2 + o], p);
            logits[(long)node * 2 + o] = p;
        }
    }
}

extern "C" void kernel_launch(void* const* d_in, const int* in_sizes, int n_in,
                              void* d_out, int out_size, void* d_ws, size_t ws_size,
                              hipStream_t stream) {
    const float* x     = (const float*)d_in[0];
    const float* sim_x = (const float*)d_in[1];
    const int* src     = (const int*)d_in[2];
    const int* dst     = (const int*)d_in[3];
    const int* sim_src = (const int*)d_in[4];
    const int* sim_dst = (const int*)d_in[5];
    const float* W1_o = (const float*)d_in[6];
    const float* b1_o = (const float*)d_in[7];
    const float* W1_s = (const float*)d_in[8];
    const float* b1_s = (const float*)d_in[9];
    const float* Wm1  = (const float*)d_in[10];
    const float* bm1  = (const float*)d_in[11];
    const float* Wm2  = (const float*)d_in[12];
    const float* bm2  = (const float*)d_in[13];

    const int N  = in_sizes[0] / 128;  // 50000
    const int E  = in_sizes[2];        // 800000
    const int Es = in_sizes[4];
    const int NF = N * 64;
    const int B  = (N + 1023) >> 10;   // 49 chunks per graph (<= 64)

    float* hall = (float*)d_out;                 // N x 384
    float* lgt  = hall + (long)N * 384;          // N x 2
    float* dinv = lgt;                           // [dinv_o N | dinv_s N] until MLP
    float* dinv_o = dinv;
    float* dinv_s = dinv + N;

    int* row_o  = (int*)d_ws;          // N+1
    int* row_s  = row_o + (N + 1);     // N+1
    int* cnt    = row_s + (N + 1);     // 2N (counts, then fill cursors)
    int* esrc_o = cnt + 2 * N;         // E
    int* esrc_s = esrc_o + E;          // Es
    int* part   = esrc_s + Es;         // 2B

    size_t ints_bytes = ((size_t)(2 * (N + 1) + 2 * N) + E + Es + 2 * B) * sizeof(int);
    size_t fbase = (ints_bytes + 255) & ~(size_t)255;
    size_t needed_big = fbase + (size_t)4 * NF * sizeof(float);
    bool bigws = ws_size >= needed_big;
    float* g0_o = (float*)((char*)d_ws + fbase);   // N x 64 dense
    float* g0_s = g0_o + NF;
    float* g1_o = g0_s + NF;
    float* g1_s = g1_o + NF;

    int nb4  = (N + 3) / 4;
    int nb64 = (N + 63) / 64;
    int nfb  = (NF + 255) / 256;
    int eb   = (E + 255) / 256;
    int ebs  = (Es + 255) / 256;

    // ---- CSR build ----
    hipMemsetAsync(cnt, 0, (size_t)(2 * N) * sizeof(int), stream);
    count2_kernel<<<eb + ebs, 256, 0, stream>>>(dst, sim_dst, cnt, E, Es, eb, N);
    scan_p1<<<2 * B, 256, 0, stream>>>(cnt, part, N, B);
    scan_p2<<<2, 64, 0, stream>>>(part, row_o, row_s, N, B);
    scan_p3<<<2 * B, 256, 0, stream>>>(cnt, part, row_o, row_s, dinv, N, B);
    hipMemcpyAsync(cnt, row_o, (size_t)N * sizeof(int), hipMemcpyDeviceToDevice, stream);
    hipMemcpyAsync(cnt + N, row_s, (size_t)N * sizeof(int), hipMemcpyDeviceToDevice, stream);
    fill2_kernel<<<eb + ebs, 256, 0, stream>>>(src, dst, sim_src, sim_dst,
                                               cnt, esrc_o, esrc_s, E, Es, eb, N);

    if (bigws) {
        // dense path: h0 -> g0 (N x 64), f1 -> g1, hop2 fuses combines into hall
        in_gemm2_kernel<<<2 * nb64, 256, 0, stream>>>(x, W1_o, b1_o, g0_o, 64,
                                                      sim_x, W1_s, b1_s, g0_s, 64, N, nb64);
        gather2x_kernel<<<2 * nb4, 256, 0, stream>>>(row_o, esrc_o, dinv_o,
                                                     row_s, esrc_s, dinv_s,
                                                     g0_o, 64, g0_s, 64,
                                                     g1_o, 64, g1_s, 64,
                                                     nullptr, 0, nullptr, 0,
                                                     hall, 0, N, nb4);
        gather2x_kernel<<<2 * nb4, 256, 0, stream>>>(row_o, esrc_o, dinv_o,
                                                     row_s, esrc_s, dinv_s,
                                                     g1_o, 64, g1_s, 64,
                                                     nullptr, 0, nullptr, 0,
                                                     g0_o, 64, g0_s, 64,
                                                     hall, 1, N, nb4);
    } else {
        // fallback: R7 hall-slot flow + standalone combine
        in_gemm2_kernel<<<2 * nb64, 256, 0, stream>>>(x, W1_o, b1_o, hall + 0, 384,
                                                      sim_x, W1_s, b1_s, hall + 192, 384, N, nb64);
        gather2x_kernel<<<2 * nb4, 256, 0, stream>>>(row_o, esrc_o, dinv_o,
                                                     row_s, esrc_s, dinv_s,
                                                     hall + 0, 384, hall + 192, 384,
                                                     hall + 64, 384, hall + 256, 384,
                                                     nullptr, 0, nullptr, 0,
                                                     hall, 0, N, nb4);
        gather2x_kernel<<<2 * nb4, 256, 0, stream>>>(row_o, esrc_o, dinv_o,
                                                     row_s, esrc_s, dinv_s,
                                                     hall + 64, 384, hall + 256, 384,
                                                     hall + 128, 384, hall + 320, 384,
                                                     nullptr, 0, nullptr, 0,
                                                     hall, 0, N, nb4);
        combine_kernel<<<nfb, 256, 0, stream>>>(hall, NF);
    }

    // ---- MLP head (overwrites dinv stash with logits) ----
    mlp_kernel<<<nb64, 256, 0, stream>>>(hall, Wm1, bm1, Wm2, bm2, lgt, N);
}